// Round 21
// baseline (65.704 us; speedup 1.0000x reference)
//
#include <hip/hip_runtime.h>
#include <hip/hip_bf16.h>

// Problem constants: B=64, Cin=3, H=W=64, O=16, k=7, fh=fw=58
#define NBUCK 2048
#define WB 0.005859375f         // bucket width 12/2048, range [-6,6)
#define SCALE 170.6666667f      // 1/WB

// output geometry
#define SEG 10092u
#define OSEG 161472u
#define OUT1 10334208u
#define NOUT 31002624u

// scratch in TAIL of d_out (fill overwrites last). float offsets:
#define TAIL_BASE (NOUT - 2097152u)    // 28,905,472 (16B aligned)
#define T_XT    0u                      // [192][4096] transposed planes
#define F_TR    786432u                 // [2049][192] F partial tables (transposed)
#define RC_TR   1179840u                // [2049][288] rc quarter tables (transposed)
#define SF_OFF  1769952u                // [192] S per F partial
#define SRC_OFF 1770144u                // [288] S per rc quarter
#define PACK    1770432u                // [3][144][64] corner pixels

typedef float v4f __attribute__((ext_vector_type(4)));

// ---------------------------------------------------------------------------
// 1) transpose: xT[plane][px][py] = x[plane][py][px] (R19-validated) so col
//    histogram blocks read coalesced. blk0 zeros the 8 gsum banks.
// ---------------------------------------------------------------------------
__global__ __launch_bounds__(256) void transpose_kernel(
    const float* __restrict__ x, float* __restrict__ tail, float* __restrict__ gsum)
{
    __shared__ float sT[64][65];
    const int plane = blockIdx.x;
    const int tid = threadIdx.x;
    if (plane == 0) { gsum[tid] = 0.f; gsum[256 + tid] = 0.f; }
    const float4* x4 = (const float4*)(x + plane * 4096);
    v4f* o4 = (v4f*)(tail + T_XT + (unsigned)plane * 4096u);
#pragma unroll
    for (int it = 0; it < 4; ++it) {
        const int i = it * 256 + tid;
        float4 v = x4[i];
        const int row = i >> 4, c4 = (i & 15) * 4;
        sT[row][c4] = v.x; sT[row][c4+1] = v.y; sT[row][c4+2] = v.z; sT[row][c4+3] = v.w;
    }
    __syncthreads();
#pragma unroll
    for (int it = 0; it < 4; ++it) {
        const int i = it * 256 + tid;
        const int px = i >> 4, py0 = (i & 15) * 4;
        v4f w = {sT[py0][px], sT[py0+1][px], sT[py0+2][px], sT[py0+3][px]};
        o4[i] = w;
    }
}

// ---------------------------------------------------------------------------
// shared scan: C/D-identity block scan of sH (R20-verbatim math), writes the
// T table TRANSPOSED at (baseT, stride, slot) and S at baseS+slot.
// ---------------------------------------------------------------------------
__device__ __forceinline__ void scan_store(
    float* sH, float* sWc, float* sWd, float* tail,
    unsigned baseT, int stride, int slot, unsigned baseS, int tid)
{
    const int lane = tid & 63;
    const int wid  = tid >> 6;
    const int b0 = 2 * tid, b1 = 2 * tid + 1;
    const float c0 = sH[b0], c1 = sH[b1];
    const float d0 = (float)b0 * c0, d1 = (float)b1 * c1;
    const float cs = c0 + c1, ds = d0 + d1;
    float ic = cs, id = ds;
#pragma unroll
    for (int off = 1; off < 64; off <<= 1) {
        const float tc = __shfl_up(ic, off);
        const float td = __shfl_up(id, off);
        if (lane >= off) { ic += tc; id += td; }
    }
    if (lane == 63) { sWc[wid] = ic; sWd[wid] = id; }
    __syncthreads();
    float baseC = 0.f, baseD = 0.f, Ntot = 0.f, Dtot = 0.f;
#pragma unroll
    for (int w = 0; w < 16; ++w) {
        const float wc = sWc[w], wd = sWd[w];
        Ntot += wc; Dtot += wd;
        if (w < wid) { baseC += wc; baseD += wd; }
    }
    const float Cex = baseC + ic - cs;
    const float Dex = baseD + id - ds;
    const float T0 = WB * (Dtot + 0.5f * Ntot);
    const float Tb0 = T0 + WB * (2.f * (float)b0 * Cex - 2.f * Dex - (float)b0 * Ntot);
    const float C1 = Cex + c0, D1 = Dex + d0;
    const float Tb1 = T0 + WB * (2.f * (float)b1 * C1 - 2.f * D1 - (float)b1 * Ntot);
    tail[baseT + (unsigned)b0 * stride + slot] = Tb0;
    tail[baseT + (unsigned)b1 * stride + slot] = Tb1;
    if (tid == 1023) {
        tail[baseT + (unsigned)NBUCK * stride + slot] =
            T0 + WB * ((float)NBUCK * Ntot - 2.f * Dtot);
        tail[baseS + slot] = T0 - 6.f * Ntot;
    }
}

// ---------------------------------------------------------------------------
// 2) build: 256 balanced blocks (R18's 4.2cyc/LDS-atomic law):
//    blk<192: F 1-plane partial (4K atomics ~17K cyc) + corner PACK.
//    blk>=192: 4-5 rc quarter-units (1K atomics each; rows from x, cols from
//    xT -- both coalesced), sequential hist->scan->store per unit.
//    Partial tables are exact by linearity; query sums them.
// ---------------------------------------------------------------------------
__global__ __launch_bounds__(1024) void build_kernel(
    const float* __restrict__ x, float* __restrict__ tail)
{
    __shared__ float sH[NBUCK];
    __shared__ float sWc[16], sWd[16];
    const int blk = blockIdx.x;
    const int tid = threadIdx.x;

    if (blk < 192) {
        sH[tid] = 0.f; sH[tid + 1024] = 0.f;
        __syncthreads();
        const int batch = blk / 3, c = blk % 3;
        float4 val = ((const float4*)x)[blk * 1024 + tid];
        float vv[4] = {val.x, val.y, val.z, val.w};
        const int pix0 = tid * 4;
        const int py = pix0 >> 6;
#pragma unroll
        for (int e = 0; e < 4; ++e) {
            const int px = (pix0 & 63) + e;
            const float v = vv[e];
            const int b = min(max((int)fmaf(v, SCALE, 1024.f), 0), NBUCK - 1);
            atomicAdd(&sH[b], 1.f);
            const bool rb = (py < 6) | (py >= 58);
            const bool cb = (px < 6) | (px >= 58);
            if (rb & cb) {
                const int ri = (py < 6) ? py : py - 52;
                const int ci = (px < 6) ? px : px - 52;
                tail[PACK + ((unsigned)c * 144 + ri * 12 + ci) * 64u + batch] = v;
            }
        }
        __syncthreads();
        scan_store(sH, sWc, sWd, tail, F_TR, 192, c * 64 + batch, SF_OFF, tid);
    } else {
        const int idx = blk - 192;                    // 0..63
        const int nu = (idx < 32) ? 5 : 4;
        const int u0 = (idx < 32) ? idx * 5 : 160 + (idx - 32) * 4;
        for (int un = 0; un < nu; ++un) {
            const int u = u0 + un;                    // 0..287
            const int c = u / 96;
            const int r2 = u - c * 96;
            const int kind = r2 / 48;
            const int r3 = r2 - kind * 48;
            const int i = r3 >> 2, qq = r3 & 3;
            sH[tid] = 0.f; sH[tid + 1024] = 0.f;
            __syncthreads();
            const int batch = qq * 16 + (tid >> 6);
            const int pos = tid & 63;
            float v;
            if (kind == 0) {
                const int py = (i < 6) ? i : i + 52;
                v = x[(batch * 3 + c) * 4096 + py * 64 + pos];
            } else {
                const int px = (i < 6) ? i : i + 52;
                v = tail[T_XT + (unsigned)((batch * 3 + c) * 4096) + px * 64 + pos];
            }
            const int b = min(max((int)fmaf(v, SCALE, 1024.f), 0), NBUCK - 1);
            atomicAdd(&sH[b], 1.f);
            __syncthreads();
            scan_store(sH, sWc, sWd, tail, RC_TR, 288, u, SRC_OFF, tid);
            __syncthreads();
        }
    }
}

// ---------------------------------------------------------------------------
// 3) query: 147 blocks x 512 = (q=hm*16+o) x (sub 0..15). Corners from LDS
//    (144 iters). F: sub s sums aligned float4 s of transposed bucket rows
//    j, j+1 (sum of partial lerps == lerp of sums). rc: subs 0..11 each sum
//    one inv-slot's 4 quarters (one aligned float4). Atomics go to 8 replica
//    gsum banks (depth 147 -> ~18; the serialized L2 tail was hidden cost).
// ---------------------------------------------------------------------------
__global__ __launch_bounds__(512) void query_kernel(
    const float* __restrict__ Kh, const float* __restrict__ Km,
    const float* __restrict__ tail, float* __restrict__ gsum)
{
    __shared__ float sC[2304];
    __shared__ float sK[32];
    __shared__ float sredA[32][16];
    __shared__ float sredL[32][16];

    const int c  = blockIdx.x / 49;
    const int t  = blockIdx.x - c * 49;
    const int dy = t / 7, dx = t - dy * 7;
    const int tid = threadIdx.x;

    for (int i = tid; i < 2304; i += 512) {
        const int cell = i >> 6, batch = i & 63;
        const int qr = cell / 6, qc = cell - qr * 6;
        const int ri = (qr < dy) ? qr : 6 + qr;
        const int ci = (qc < dx) ? qc : 6 + qc;
        sC[i] = tail[PACK + ((unsigned)c * 144 + ri * 12 + ci) * 64u + batch];
    }
    if (tid < 32)
        sK[tid] = ((tid >= 16) ? Km : Kh)[(tid & 15) * 147 + c * 49 + t];
    __syncthreads();

    const int q   = tid >> 4;
    const int sub = tid & 15;
    const float k = sK[q];

    float accA = 0.f, accL = 0.f;
#pragma unroll 16
    for (int step = 0; step < 144; ++step) {          // exact corners
        const float v = sC[sub + 16 * step];
        accA += fabsf(k - v);
        accL += k - v;
    }

    const float u = fmaf(k, SCALE, 1024.f);
    const int j = min(max((int)u, 0), NBUCK - 1);
    const float fr = u - (float)j;

    {   // F: one aligned float4 of 64-slot channel segment per sub
        const v4f f0 = *(const v4f*)(tail + F_TR + (unsigned)j * 192u + c * 64 + sub * 4);
        const v4f f1 = *(const v4f*)(tail + F_TR + (unsigned)(j + 1) * 192u + c * 64 + sub * 4);
        const float s0 = f0.x + f0.y + f0.z + f0.w;
        const float s1 = f1.x + f1.y + f1.z + f1.w;
        accA += s0 + fr * (s1 - s0);
        const v4f sf = *(const v4f*)(tail + SF_OFF + c * 64 + sub * 4);
        accL -= sf.x + sf.y + sf.z + sf.w;
        if (sub == 0) accL += k * 212992.f;           // (58*58-36)*64
    }
    if (sub < 12) {  // rc: one inv-slot (4 quarters = aligned float4)
        int base_f4;
        if (sub < 6) {
            const int ri = (sub < dy) ? sub : 6 + sub;
            base_f4 = c * 96 + ri * 4;
        } else {
            const int s6 = sub - 6;
            const int ci = (s6 < dx) ? s6 : 6 + s6;
            base_f4 = c * 96 + 48 + ci * 4;
        }
        const v4f r0 = *(const v4f*)(tail + RC_TR + (unsigned)j * 288u + base_f4);
        const v4f r1 = *(const v4f*)(tail + RC_TR + (unsigned)(j + 1) * 288u + base_f4);
        const float s0 = r0.x + r0.y + r0.z + r0.w;
        const float s1 = r1.x + r1.y + r1.z + r1.w;
        accA -= s0 + fr * (s1 - s0);
        const v4f sr = *(const v4f*)(tail + SRC_OFF + base_f4);
        accL += sr.x + sr.y + sr.z + sr.w;
    }

    sredA[q][sub] = accA;
    sredL[q][sub] = accL;
    __syncthreads();
    if (tid < 64) {
        const int idx  = tid >> 1;
        const int part = tid & 1;
        const float (*sr)[16] = part ? sredL : sredA;
        float s = 0.f;
#pragma unroll
        for (int e = 0; e < 16; ++e) s += sr[idx][e];
        atomicAdd(&gsum[(blockIdx.x & 7) * 64 + part * 32 + idx], s);
    }
}

// ---------------------------------------------------------------------------
// 4) fill: sum 8 banks, fold -> s_hit/s_miss; broadcast-fill 124 MB.
// ---------------------------------------------------------------------------
__global__ __launch_bounds__(256) void fill_kernel(
    const float* __restrict__ gsum, v4f* __restrict__ out, unsigned n4)
{
    __shared__ float sv[48];
    if (threadIdx.x < 48) {
        const int o = threadIdx.x & 15, grp = threadIdx.x >> 4;
        float Ah = 0.f, Am = 0.f, Lh = 0.f, Lm = 0.f;
#pragma unroll
        for (int b = 0; b < 8; ++b) {
            Ah += gsum[b * 64 + o];      Am += gsum[b * 64 + 16 + o];
            Lh += gsum[b * 64 + 32 + o]; Lm += gsum[b * 64 + 48 + o];
        }
        const float h = -0.5f * (Lh + Ah);
        const float m =  0.5f * (Am - Lm);
        sv[threadIdx.x] = (grp == 0) ? (h - m) : ((grp == 1) ? h : m);
    }
    __syncthreads();
    const unsigned stride = gridDim.x * blockDim.x;
    for (unsigned i = blockIdx.x * blockDim.x + threadIdx.x; i < n4; i += stride) {
        const unsigned f = i * 4u;
        const unsigned w   = f / OUT1;
        const unsigned rem = f - w * OUT1;
        const unsigned o   = (rem % OSEG) / SEG;
        const float val = sv[w * 16 + o];
        v4f pk = {val, val, val, val};
        __builtin_nontemporal_store(pk, &out[i]);
    }
}

extern "C" void kernel_launch(void* const* d_in, const int* in_sizes, int n_in,
                              void* d_out, int out_size, void* d_ws, size_t ws_size,
                              hipStream_t stream)
{
    const float* x  = (const float*)d_in[0];
    const float* Kh = (const float*)d_in[1];
    const float* Km = (const float*)d_in[2];
    float* out  = (float*)d_out;
    float* tail = out + TAIL_BASE;
    float* gsum = (float*)d_ws;    // 512 floats: 8 banks x 64

    transpose_kernel<<<192, 256, 0, stream>>>(x, tail, gsum);
    build_kernel    <<<256, 1024, 0, stream>>>(x, tail);
    query_kernel    <<<147, 512, 0, stream>>>(Kh, Km, tail, gsum);
    fill_kernel     <<<4096, 256, 0, stream>>>(gsum, (v4f*)out, NOUT / 4u);
}

// Round 22
// 50.834 us; speedup vs baseline: 1.2925x; 1.2925x over previous
//
#include <hip/hip_runtime.h>
#include <hip/hip_bf16.h>

// Problem constants: B=64, Cin=3, H=W=64, O=16, k=7, fh=fw=58
#define NBUCK 2048
#define WB 0.005859375f         // bucket width 12/2048, range [-6,6)
#define SCALE 170.6666667f      // 1/WB

// output geometry
#define SEG 10092u
#define OSEG 161472u
#define OUT1 10334208u
#define NOUT 31002624u

// scratch in TAIL of d_out (fill overwrites last). float offsets:
// F partials TRANSPOSED: F_tr[bucket][192 slots = c*64+batch]
// rc quarters TRANSPOSED: RC_tr[bucket][288 = c*96 + kind*48 + i*4 + qtr]
#define TAIL_BASE (NOUT - 1310720u)    // 29,691,904 (16B aligned)
#define F_TR    0u                      // [2049][192] = 393,408
#define RC_TR   393408u                 // [2049][288] = 590,112
#define SF_OFF  983520u                 // [192]
#define SRC_OFF 983712u                 // [288]
#define PACK    984000u                 // [3][144][64] corner pixels

typedef float v4f __attribute__((ext_vector_type(4)));

// ---------------------------------------------------------------------------
// shared scan: C/D-identity block scan of sH (R20-verbatim math), writes the
// T table TRANSPOSED at (baseT, stride, slot) and S at baseS+slot.
// ---------------------------------------------------------------------------
__device__ __forceinline__ void scan_store(
    float* sH, float* sWc, float* sWd, float* tail,
    unsigned baseT, int stride, int slot, unsigned baseS, int tid)
{
    const int lane = tid & 63;
    const int wid  = tid >> 6;
    const int b0 = 2 * tid, b1 = 2 * tid + 1;
    const float c0 = sH[b0], c1 = sH[b1];
    const float d0 = (float)b0 * c0, d1 = (float)b1 * c1;
    const float cs = c0 + c1, ds = d0 + d1;
    float ic = cs, id = ds;
#pragma unroll
    for (int off = 1; off < 64; off <<= 1) {
        const float tc = __shfl_up(ic, off);
        const float td = __shfl_up(id, off);
        if (lane >= off) { ic += tc; id += td; }
    }
    if (lane == 63) { sWc[wid] = ic; sWd[wid] = id; }
    __syncthreads();
    float baseC = 0.f, baseD = 0.f, Ntot = 0.f, Dtot = 0.f;
#pragma unroll
    for (int w = 0; w < 16; ++w) {
        const float wc = sWc[w], wd = sWd[w];
        Ntot += wc; Dtot += wd;
        if (w < wid) { baseC += wc; baseD += wd; }
    }
    const float Cex = baseC + ic - cs;
    const float Dex = baseD + id - ds;
    const float T0 = WB * (Dtot + 0.5f * Ntot);
    const float Tb0 = T0 + WB * (2.f * (float)b0 * Cex - 2.f * Dex - (float)b0 * Ntot);
    const float C1 = Cex + c0, D1 = Dex + d0;
    const float Tb1 = T0 + WB * (2.f * (float)b1 * C1 - 2.f * D1 - (float)b1 * Ntot);
    tail[baseT + (unsigned)b0 * stride + slot] = Tb0;
    tail[baseT + (unsigned)b1 * stride + slot] = Tb1;
    if (tid == 1023) {
        tail[baseT + (unsigned)NBUCK * stride + slot] =
            T0 + WB * ((float)NBUCK * Ntot - 2.f * Dtot);
        tail[baseS + slot] = T0 - 6.f * Ntot;
    }
}

// ---------------------------------------------------------------------------
// 1) build: 480 blocks, ONE hist+scan each (R21 lesson: never serialize
//    units per block at ~1 block/CU).
//    blk<192: F 1-plane partial (4K atomics, halves R20's F critical path)
//             + corner PACK. slot = c*64+batch.
//    blk>=192: rc quarter-unit u=blk-192 (1K atomics; rows coalesced, cols
//             = 1 scattered load/thread, single latency burst).
// ---------------------------------------------------------------------------
__global__ __launch_bounds__(1024) void build_kernel(
    const float* __restrict__ x, float* __restrict__ tail, float* __restrict__ gsum)
{
    __shared__ float sH[NBUCK];
    __shared__ float sWc[16], sWd[16];
    const int blk = blockIdx.x;
    const int tid = threadIdx.x;
    sH[tid] = 0.f; sH[tid + 1024] = 0.f;
    if (blk == 0 && tid < 512) gsum[tid] = 0.f;
    __syncthreads();

    if (blk < 192) {
        const int batch = blk / 3, c = blk % 3;     // plane == blk
        float4 val = ((const float4*)x)[blk * 1024 + tid];
        float vv[4] = {val.x, val.y, val.z, val.w};
        const int pix0 = tid * 4;
        const int py = pix0 >> 6;
#pragma unroll
        for (int e = 0; e < 4; ++e) {
            const int px = (pix0 & 63) + e;
            const float v = vv[e];
            const int b = min(max((int)fmaf(v, SCALE, 1024.f), 0), NBUCK - 1);
            atomicAdd(&sH[b], 1.f);
            const bool rb = (py < 6) | (py >= 58);
            const bool cb = (px < 6) | (px >= 58);
            if (rb & cb) {
                const int ri = (py < 6) ? py : py - 52;
                const int ci = (px < 6) ? px : px - 52;
                tail[PACK + ((unsigned)c * 144 + ri * 12 + ci) * 64u + batch] = v;
            }
        }
        __syncthreads();
        scan_store(sH, sWc, sWd, tail, F_TR, 192, c * 64 + batch, SF_OFF, tid);
    } else {
        const int u = blk - 192;                    // 0..287
        const int c = u / 96;
        const int r2 = u - c * 96;
        const int kind = r2 / 48;                   // 0=row, 1=col
        const int r3 = r2 - kind * 48;
        const int i = r3 >> 2, qtr = r3 & 3;
        const int batch = qtr * 16 + (tid >> 6);
        const int pos = tid & 63;
        float v;
        if (kind == 0) {
            const int py = (i < 6) ? i : i + 52;
            v = x[(batch * 3 + c) * 4096 + py * 64 + pos];      // coalesced
        } else {
            const int px = (i < 6) ? i : i + 52;
            v = x[(batch * 3 + c) * 4096 + pos * 64 + px];      // 1 scattered load/thread
        }
        const int b = min(max((int)fmaf(v, SCALE, 1024.f), 0), NBUCK - 1);
        atomicAdd(&sH[b], 1.f);
        __syncthreads();
        scan_store(sH, sWc, sWd, tail, RC_TR, 288, u, SRC_OFF, tid);
    }
}

// ---------------------------------------------------------------------------
// 2) query: 147 blocks x 512 = (q=hm*16+o) x (sub 0..15).
//    PACK staged via float4 (576 loads). F: sub sums its aligned float4 of
//    the 64-slot channel segment at bucket rows j, j+1 (sum of partial
//    lerps == lerp of sums). rc: subs 0..11 sum one inv-slot's 4 quarters
//    (one aligned float4). Atomics -> 8 replica gsum banks (depth ~18).
// ---------------------------------------------------------------------------
__global__ __launch_bounds__(512) void query_kernel(
    const float* __restrict__ Kh, const float* __restrict__ Km,
    const float* __restrict__ tail, float* __restrict__ gsum)
{
    __shared__ float sC[2304];
    __shared__ float sK[32];
    __shared__ float sredA[32][16];
    __shared__ float sredL[32][16];

    const int c  = blockIdx.x / 49;
    const int t  = blockIdx.x - c * 49;
    const int dy = t / 7, dx = t - dy * 7;
    const int tid = threadIdx.x;

    for (int i = tid; i < 576; i += 512) {          // float4 staging
        const int cell = i >> 4, b4 = i & 15;
        const int qr = cell / 6, qc = cell - qr * 6;
        const int ri = (qr < dy) ? qr : 6 + qr;
        const int ci = (qc < dx) ? qc : 6 + qc;
        ((v4f*)sC)[i] = *(const v4f*)(tail + PACK +
            ((unsigned)c * 144 + ri * 12 + ci) * 64u + b4 * 4);
    }
    if (tid < 32)
        sK[tid] = ((tid >= 16) ? Km : Kh)[(tid & 15) * 147 + c * 49 + t];
    __syncthreads();

    const int q   = tid >> 4;
    const int sub = tid & 15;
    const float k = sK[q];

    float accA = 0.f, accL = 0.f;
#pragma unroll 16
    for (int step = 0; step < 144; ++step) {        // exact corners
        const float v = sC[sub + 16 * step];
        accA += fabsf(k - v);
        accL += k - v;
    }

    const float u = fmaf(k, SCALE, 1024.f);
    const int j = min(max((int)u, 0), NBUCK - 1);
    const float fr = u - (float)j;

    {   // F: one aligned float4 of the 64-slot channel segment per sub
        const v4f f0 = *(const v4f*)(tail + F_TR + (unsigned)j * 192u + c * 64 + sub * 4);
        const v4f f1 = *(const v4f*)(tail + F_TR + (unsigned)(j + 1) * 192u + c * 64 + sub * 4);
        const float s0 = f0.x + f0.y + f0.z + f0.w;
        const float s1 = f1.x + f1.y + f1.z + f1.w;
        accA += s0 + fr * (s1 - s0);
        const v4f sf = *(const v4f*)(tail + SF_OFF + c * 64 + sub * 4);
        accL -= sf.x + sf.y + sf.z + sf.w;
        if (sub == 0) accL += k * 212992.f;         // (58*58-36)*64
    }
    if (sub < 12) {   // rc: one inv-slot (4 quarters = aligned float4)
        int base_f4;
        if (sub < 6) {
            const int ri = (sub < dy) ? sub : 6 + sub;
            base_f4 = c * 96 + ri * 4;
        } else {
            const int s6 = sub - 6;
            const int ci = (s6 < dx) ? s6 : 6 + s6;
            base_f4 = c * 96 + 48 + ci * 4;
        }
        const v4f r0 = *(const v4f*)(tail + RC_TR + (unsigned)j * 288u + base_f4);
        const v4f r1 = *(const v4f*)(tail + RC_TR + (unsigned)(j + 1) * 288u + base_f4);
        const float s0 = r0.x + r0.y + r0.z + r0.w;
        const float s1 = r1.x + r1.y + r1.z + r1.w;
        accA -= s0 + fr * (s1 - s0);
        const v4f sr = *(const v4f*)(tail + SRC_OFF + base_f4);
        accL += sr.x + sr.y + sr.z + sr.w;
    }

    sredA[q][sub] = accA;
    sredL[q][sub] = accL;
    __syncthreads();
    if (tid < 64) {
        const int idx  = tid >> 1;
        const int part = tid & 1;
        const float (*sr)[16] = part ? sredL : sredA;
        float s = 0.f;
#pragma unroll
        for (int e = 0; e < 16; ++e) s += sr[idx][e];
        atomicAdd(&gsum[(blockIdx.x & 7) * 64 + part * 32 + idx], s);
    }
}

// ---------------------------------------------------------------------------
// 3) fill: sum 8 banks, fold -> s_hit/s_miss; broadcast-fill 124 MB.
// ---------------------------------------------------------------------------
__global__ __launch_bounds__(256) void fill_kernel(
    const float* __restrict__ gsum, v4f* __restrict__ out, unsigned n4)
{
    __shared__ float sv[48];
    if (threadIdx.x < 48) {
        const int o = threadIdx.x & 15, grp = threadIdx.x >> 4;
        float Ah = 0.f, Am = 0.f, Lh = 0.f, Lm = 0.f;
#pragma unroll
        for (int b = 0; b < 8; ++b) {
            Ah += gsum[b * 64 + o];      Am += gsum[b * 64 + 16 + o];
            Lh += gsum[b * 64 + 32 + o]; Lm += gsum[b * 64 + 48 + o];
        }
        const float h = -0.5f * (Lh + Ah);
        const float m =  0.5f * (Am - Lm);
        sv[threadIdx.x] = (grp == 0) ? (h - m) : ((grp == 1) ? h : m);
    }
    __syncthreads();
    const unsigned stride = gridDim.x * blockDim.x;
    for (unsigned i = blockIdx.x * blockDim.x + threadIdx.x; i < n4; i += stride) {
        const unsigned f = i * 4u;
        const unsigned w   = f / OUT1;
        const unsigned rem = f - w * OUT1;
        const unsigned o   = (rem % OSEG) / SEG;
        const float val = sv[w * 16 + o];
        v4f pk = {val, val, val, val};
        __builtin_nontemporal_store(pk, &out[i]);
    }
}

extern "C" void kernel_launch(void* const* d_in, const int* in_sizes, int n_in,
                              void* d_out, int out_size, void* d_ws, size_t ws_size,
                              hipStream_t stream)
{
    const float* x  = (const float*)d_in[0];
    const float* Kh = (const float*)d_in[1];
    const float* Km = (const float*)d_in[2];
    float* out  = (float*)d_out;
    float* tail = out + TAIL_BASE;
    float* gsum = (float*)d_ws;    // 512 floats: 8 banks x 64

    build_kernel<<<480, 1024, 0, stream>>>(x, tail, gsum);
    query_kernel<<<147, 512, 0, stream>>>(Kh, Km, tail, gsum);
    fill_kernel <<<4096, 256, 0, stream>>>(gsum, (v4f*)out, NOUT / 4u);
}